// Round 21
// baseline (72.115 us; speedup 1.0000x reference)
//
#include <hip/hip_runtime.h>
#include <hip/hip_bf16.h>

// Problem constants
#define B_  64
#define N1_ 8
#define KK  128
#define EE  256
#define HH  512
#define BN  (B_ * N1_)   // 512

typedef __attribute__((ext_vector_type(8))) short short8;   // bf16x8 MFMA frag
typedef __attribute__((ext_vector_type(4))) float f32x4;    // MFMA acc

__device__ __forceinline__ short bfs(float f) {
  __hip_bfloat16 h = __float2bfloat16(f);   // RNE
  return __builtin_bit_cast(short, h);
}
__device__ __forceinline__ float tanhf_fast(float x) {
  float e2 = __builtin_amdgcn_exp2f(2.8853900817779268f * x);  // exp(2x)
  return 1.0f - 2.0f * __builtin_amdgcn_rcpf(e2 + 1.0f);
}

// ---------------------------------------------------------------------------
// k_prep (unchanged, passing since r17):
//  blocks 0..63   -> wk_w -> FRAGMENT-MAJOR bf16 wk_fr:
//     chunk ((ht*8+s)*64 + lane)[8] = wk[ht*16+(lane&15)][(lane>>4)*8+s*32..]
//  blocks 64..127 -> qproj MFMA: qp[bn][h] = q.wq[h] + wq_b[h] + wk_b[h]
// MFMA frag [m89]: A row=lane&15, e=(lane>>4)*8+s*32; D col=lane&15,
// row=(lane>>4)*4+reg.
// ---------------------------------------------------------------------------
__global__ __launch_bounds__(256) void k_prep(
    const float* __restrict__ wk_w,
    const float* __restrict__ queries,
    const float* __restrict__ wq_w,
    const float* __restrict__ wq_b,
    const float* __restrict__ wk_b,
    unsigned short* __restrict__ wk_fr,
    float* __restrict__ qp) {
  const int bid = blockIdx.x, t = threadIdx.x;
  if (bid < 64) {
    const int g  = bid * 256 + t;           // chunk id 0..16383
    const int h  = g >> 5;
    const int e0 = (g & 31) * 8;
    float4 x = *(const float4*)(wk_w + (size_t)h * EE + e0);
    float4 y = *(const float4*)(wk_w + (size_t)h * EE + e0 + 4);
    short8 f;
    f[0] = bfs(x.x); f[1] = bfs(x.y); f[2] = bfs(x.z); f[3] = bfs(x.w);
    f[4] = bfs(y.x); f[5] = bfs(y.y); f[6] = bfs(y.z); f[7] = bfs(y.w);
    const int ht = h >> 4, hl = h & 15;
    const int s = e0 >> 5, lg = (e0 >> 3) & 3;
    const int chunk = (ht * 8 + s) * 64 + lg * 16 + hl;
    *(short8*)(wk_fr + (size_t)chunk * 8) = f;
  } else {
    const int w = t >> 6, l = t & 63, lg = l >> 4, ll = l & 15;
    const int g2 = bid - 64;                // 0..63
    const int bn0 = (g2 >> 1) * 16;
    const int ht0 = (g2 & 1) * 16;
    short8 af[8];
    {
      const float* qr = queries + (size_t)(bn0 + ll) * EE + lg * 8;
      #pragma unroll
      for (int s = 0; s < 8; ++s) {
        float4 x = *(const float4*)(qr + s * 32);
        float4 y = *(const float4*)(qr + s * 32 + 4);
        short8 f;
        f[0] = bfs(x.x); f[1] = bfs(x.y); f[2] = bfs(x.z); f[3] = bfs(x.w);
        f[4] = bfs(y.x); f[5] = bfs(y.y); f[6] = bfs(y.z); f[7] = bfs(y.w);
        af[s] = f;
      }
    }
    #pragma unroll
    for (int i = 0; i < 4; ++i) {
      const int ht = ht0 + w * 4 + i;
      const float* bp = wq_w + (size_t)(ht * 16 + ll) * EE + lg * 8;
      f32x4 a = {0.f, 0.f, 0.f, 0.f};
      #pragma unroll
      for (int s = 0; s < 8; ++s) {
        float4 x = *(const float4*)(bp + s * 32);
        float4 y = *(const float4*)(bp + s * 32 + 4);
        short8 f;
        f[0] = bfs(x.x); f[1] = bfs(x.y); f[2] = bfs(x.z); f[3] = bfs(x.w);
        f[4] = bfs(y.x); f[5] = bfs(y.y); f[6] = bfs(y.z); f[7] = bfs(y.w);
        a = __builtin_amdgcn_mfma_f32_16x16x32_bf16(af[s], f, a, 0, 0, 0);
      }
      const int h = ht * 16 + ll;
      const float add = wq_b[h] + wk_b[h];
      #pragma unroll
      for (int r = 0; r < 4; ++r)
        qp[(size_t)(bn0 + lg * 4 + r) * HH + h] = a[r] + add;
    }
  }
}

// ---------------------------------------------------------------------------
// k_scores: grid 2048 = 512 bn x 4 h-quarters. 512 thr = 8 waves.
// Wave w owns rows bn*128 + w*16 .. +15; covers its quarter's 128 h.
// B-QUARTER (64 KB, fragment-major) staged into LDS ONCE -> the h-loop has
// ZERO barriers and ZERO global loads: pure ds_read_b128 + MFMA + tanh.
// 2 blocks/CU (130 KB LDS) x 8 waves = 4 waves/SIMD — 2x any prior round.
// Writes quarter-partial scores scp[row][q].
// MFMA 16x16x32 C/D: col(h)=lane&15, row(key)=(lane>>4)*4+reg   [m89].
// ---------------------------------------------------------------------------
__global__ __launch_bounds__(512, 4) void k_scores(
    const float* __restrict__ keys,
    const unsigned short* __restrict__ wk_fr,
    const float* __restrict__ wv_w,
    const float* __restrict__ qp,
    float* __restrict__ scp) {
  const int t  = threadIdx.x;
  const int w  = t >> 6;      // wave 0..7
  const int l  = t & 63;
  const int lg = l >> 4;      // lane group 0..3
  const int ll = l & 15;
  const int bid = blockIdx.x;
  const int bn  = bid >> 2;
  const int q   = bid & 3;    // h-quarter

  __shared__ __align__(16) char bq[8 * 8192];   // 64 KB: tiles q*8 .. q*8+7
  __shared__ float2 qw_s[128];                  // quarter's {qb, wv}

  // stage B quarter: 4096 16-B chunks, 512 threads x 8 (coalesced copy)
  {
    const float4* src = (const float4*)((const char*)wk_fr + (size_t)q * 8 * 8192);
    float4* dst = (float4*)bq;
    #pragma unroll
    for (int j = 0; j < 8; ++j) dst[t + j * 512] = src[t + j * 512];
  }
  if (t < 128) {
    float2 v; v.x = qp[(size_t)bn * HH + q * 128 + t]; v.y = wv_w[q * 128 + t];
    qw_s[t] = v;
  }

  // A-frags: this wave's 16 rows of keys -> bf16 (1 chain x 8 slots)
  short8 af[8];
  {
    const float* kp = keys + (size_t)(bn * KK + w * 16 + ll) * EE + lg * 8;
    #pragma unroll
    for (int s = 0; s < 8; ++s) {
      float4 x = *(const float4*)(kp + s * 32);
      float4 y = *(const float4*)(kp + s * 32 + 4);
      short8 f;
      f[0] = bfs(x.x); f[1] = bfs(x.y); f[2] = bfs(x.z); f[3] = bfs(x.w);
      f[4] = bfs(y.x); f[5] = bfs(y.y); f[6] = bfs(y.z); f[7] = bfs(y.w);
      af[s] = f;
    }
  }
  __syncthreads();    // B quarter + qw ready; only barrier in the kernel

  float p[4] = {0.f, 0.f, 0.f, 0.f};

  #pragma unroll
  for (int i = 0; i < 8; ++i) {       // 8 h-tiles of this quarter
    const char* bt = bq + i * 8192;
    f32x4 a0 = {0.f, 0.f, 0.f, 0.f};  // 2 chains x depth 4
    f32x4 a1 = {0.f, 0.f, 0.f, 0.f};
    #pragma unroll
    for (int s = 0; s < 4; ++s) {
      short8 b0 = *(const short8*)(bt + s * 1024 + l * 16);
      short8 b1 = *(const short8*)(bt + (s + 4) * 1024 + l * 16);
      a0 = __builtin_amdgcn_mfma_f32_16x16x32_bf16(af[s], b0, a0, 0, 0, 0);
      a1 = __builtin_amdgcn_mfma_f32_16x16x32_bf16(af[s + 4], b1, a1, 0, 0, 0);
    }
    const float2 qw = qw_s[i * 16 + ll];
    #pragma unroll
    for (int r = 0; r < 4; ++r)
      p[r] += qw.y * tanhf_fast(a0[r] + a1[r] + qw.x);
  }

  // reduce over the 16 h-lanes (ll) of each lane group
  #pragma unroll
  for (int r = 0; r < 4; ++r) {
    #pragma unroll
    for (int off = 1; off <= 8; off <<= 1)
      p[r] += __shfl_xor(p[r], off, 64);
  }
  if (ll == 0) {
    #pragma unroll
    for (int r = 0; r < 4; ++r)
      scp[(size_t)(bn * KK + w * 16 + lg * 4 + r) * 4 + q] = p[r];
  }
}

// ---------------------------------------------------------------------------
// k_smout: per bn: sum quarter-partials, masked softmax over K=128,
// write attn_weight, then attn_out via float4 PV (8-way k-split, f32 keys).
// ---------------------------------------------------------------------------
__global__ __launch_bounds__(512) void k_smout(
    const float* __restrict__ keys,
    const int* __restrict__ masks,
    const float* __restrict__ scp,
    float* __restrict__ out) {
  const int bn = blockIdx.x;
  const int t  = threadIdx.x;
  __shared__ float sc[KK];
  __shared__ float4 po4[8][64];
  __shared__ float red[2];

  if (t < KK) {
    float4 s4 = ((const float4*)scp)[(size_t)bn * KK + t];
    sc[t] = s4.x + s4.y + s4.z + s4.w + (float)masks[bn * KK + t] * (-1e9f);
  }
  __syncthreads();
  if (t < 64) {
    float a = fmaxf(sc[t], sc[t + 64]);
    #pragma unroll
    for (int off = 32; off >= 1; off >>= 1) a = fmaxf(a, __shfl_xor(a, off, 64));
    if (t == 0) red[0] = a;
  }
  __syncthreads();
  const float m = red[0];
  if (t < KK) sc[t] = expf(sc[t] - m);
  __syncthreads();
  if (t < 64) {
    float a = sc[t] + sc[t + 64];
    #pragma unroll
    for (int off = 32; off >= 1; off >>= 1) a += __shfl_xor(a, off, 64);
    if (t == 0) red[1] = a;
  }
  __syncthreads();
  const float inv = 1.f / red[1];
  if (t < KK) {
    float wgt = sc[t] * inv;
    sc[t] = wgt;
    out[BN * EE + (size_t)bn * KK + t] = wgt;   // attn_weight
  }
  __syncthreads();

  // PV: float4 over e, 8-way k-split (16 k each)
  {
    const float4* kb4 = (const float4*)(keys + (size_t)bn * KK * EE);
    const int kh = t >> 6, ln = t & 63;
    float4 acc = {0.f, 0.f, 0.f, 0.f};
    #pragma unroll 4
    for (int k = 0; k < 16; ++k) {
      const float wgt = sc[kh * 16 + k];
      float4 kv = kb4[(size_t)(kh * 16 + k) * 64 + ln];
      acc.x += wgt * kv.x; acc.y += wgt * kv.y;
      acc.z += wgt * kv.z; acc.w += wgt * kv.w;
    }
    po4[kh][ln] = acc;
  }
  __syncthreads();
  if (t < 64) {
    float4 r = po4[0][t];
    #pragma unroll
    for (int g = 1; g < 8; ++g) {
      float4 a = po4[g][t];
      r.x += a.x; r.y += a.y; r.z += a.z; r.w += a.w;
    }
    *(float4*)(out + (size_t)bn * EE + t * 4) = r;
  }
}

// ---------------------------------------------------------------------------
extern "C" void kernel_launch(void* const* d_in, const int* in_sizes, int n_in,
                              void* d_out, int out_size, void* d_ws, size_t ws_size,
                              hipStream_t stream) {
  const float* queries = (const float*)d_in[0];
  const float* keys    = (const float*)d_in[1];
  const int*   masks   = (const int*)d_in[2];
  // d_in[3] = num_neg (unused)
  const float* wk_w = (const float*)d_in[4];
  const float* wk_b = (const float*)d_in[5];
  const float* wq_w = (const float*)d_in[6];
  const float* wq_b = (const float*)d_in[7];
  const float* wv_w = (const float*)d_in[8];
  // d_in[9] = wv_b (softmax shift-invariant -> unused)

  float* out = (float*)d_out;
  float* qp  = (float*)d_ws;                                 // 1 MB
  unsigned short* wk_fr = (unsigned short*)(qp + BN * HH);   // 256 KB
  float* scp = (float*)(wk_fr + HH * EE);                    // 65536*4 f32 = 1 MB

  k_prep<<<128, 256, 0, stream>>>(wk_w, queries, wq_w, wq_b, wk_b, wk_fr, qp);
  k_scores<<<BN * 4, 512, 0, stream>>>(keys, wk_fr, wv_w, qp, scp);
  k_smout<<<BN, 512, 0, stream>>>(keys, masks, scp, out);
}

// Round 22
// 49.805 us; speedup vs baseline: 1.4480x; 1.4480x over previous
//
#include <hip/hip_runtime.h>
#include <hip/hip_bf16.h>

// Problem constants
#define B_  64
#define N1_ 8
#define KK  128
#define EE  256
#define HH  512
#define BN  (B_ * N1_)   // 512

typedef __attribute__((ext_vector_type(8))) short short8;   // bf16x8 MFMA frag
typedef __attribute__((ext_vector_type(4))) float f32x4;    // MFMA acc

__device__ __forceinline__ short bfs(float f) {
  __hip_bfloat16 h = __float2bfloat16(f);   // RNE
  return __builtin_bit_cast(short, h);
}
__device__ __forceinline__ float bf2f(short s) {
  unsigned int u = ((unsigned int)(unsigned short)s) << 16;
  return __builtin_bit_cast(float, u);
}
__device__ __forceinline__ float tanhf_fast(float x) {
  float e2 = __builtin_amdgcn_exp2f(2.8853900817779268f * x);  // exp(2x)
  return 1.0f - 2.0f * __builtin_amdgcn_rcpf(e2 + 1.0f);
}

// ---------------------------------------------------------------------------
// k_prep:
//  blocks 0..63   -> wk_w -> FRAGMENT-MAJOR bf16 wk_fr:
//     chunk ((ht*8+s)*64 + lane)[8] = wk[ht*16+(lane&15)][(lane>>4)*8+s*32..]
//  blocks 64..127 -> qproj MFMA: qp[bn][h] = q.wq[h] + wq_b[h] + wk_b[h]
// MFMA frag [m89]: A row=lane&15, e=(lane>>4)*8+s*32; D col=lane&15,
// row=(lane>>4)*4+reg.
// ---------------------------------------------------------------------------
__global__ __launch_bounds__(256) void k_prep(
    const float* __restrict__ wk_w,
    const float* __restrict__ queries,
    const float* __restrict__ wq_w,
    const float* __restrict__ wq_b,
    const float* __restrict__ wk_b,
    unsigned short* __restrict__ wk_fr,
    float* __restrict__ qp) {
  const int bid = blockIdx.x, t = threadIdx.x;
  if (bid < 64) {
    const int g  = bid * 256 + t;           // chunk id 0..16383
    const int h  = g >> 5;
    const int e0 = (g & 31) * 8;
    float4 x = *(const float4*)(wk_w + (size_t)h * EE + e0);
    float4 y = *(const float4*)(wk_w + (size_t)h * EE + e0 + 4);
    short8 f;
    f[0] = bfs(x.x); f[1] = bfs(x.y); f[2] = bfs(x.z); f[3] = bfs(x.w);
    f[4] = bfs(y.x); f[5] = bfs(y.y); f[6] = bfs(y.z); f[7] = bfs(y.w);
    const int ht = h >> 4, hl = h & 15;
    const int s = e0 >> 5, lg = (e0 >> 3) & 3;
    const int chunk = (ht * 8 + s) * 64 + lg * 16 + hl;
    *(short8*)(wk_fr + (size_t)chunk * 8) = f;
  } else {
    const int w = t >> 6, l = t & 63, lg = l >> 4, ll = l & 15;
    const int g2 = bid - 64;                // 0..63
    const int bn0 = (g2 >> 1) * 16;
    const int ht0 = (g2 & 1) * 16;
    short8 af[8];
    {
      const float* qr = queries + (size_t)(bn0 + ll) * EE + lg * 8;
      #pragma unroll
      for (int s = 0; s < 8; ++s) {
        float4 x = *(const float4*)(qr + s * 32);
        float4 y = *(const float4*)(qr + s * 32 + 4);
        short8 f;
        f[0] = bfs(x.x); f[1] = bfs(x.y); f[2] = bfs(x.z); f[3] = bfs(x.w);
        f[4] = bfs(y.x); f[5] = bfs(y.y); f[6] = bfs(y.z); f[7] = bfs(y.w);
        af[s] = f;
      }
    }
    #pragma unroll
    for (int i = 0; i < 4; ++i) {
      const int ht = ht0 + w * 4 + i;
      const float* bp = wq_w + (size_t)(ht * 16 + ll) * EE + lg * 8;
      f32x4 a = {0.f, 0.f, 0.f, 0.f};
      #pragma unroll
      for (int s = 0; s < 8; ++s) {
        float4 x = *(const float4*)(bp + s * 32);
        float4 y = *(const float4*)(bp + s * 32 + 4);
        short8 f;
        f[0] = bfs(x.x); f[1] = bfs(x.y); f[2] = bfs(x.z); f[3] = bfs(x.w);
        f[4] = bfs(y.x); f[5] = bfs(y.y); f[6] = bfs(y.z); f[7] = bfs(y.w);
        a = __builtin_amdgcn_mfma_f32_16x16x32_bf16(af[s], f, a, 0, 0, 0);
      }
      const int h = ht * 16 + ll;
      const float add = wq_b[h] + wk_b[h];
      #pragma unroll
      for (int r = 0; r < 4; ++r)
        qp[(size_t)(bn0 + lg * 4 + r) * HH + h] = a[r] + add;
    }
  }
}

// ---------------------------------------------------------------------------
// k_fused (round-17 best-measured: 44-47 us): one block = one bn. 4 waves x
// 32 rows; every wave covers all 512 h. Keys read ONCE (A-frags in regs; PV
// computed from them in-register). B: hand-held ASM register pipeline, 2
// tiles deep; early-clobber "=&v" outputs; bare s_waitcnt vmcnt(N) +
// sched_barrier(0) release (rule #18). NO barriers in the loop.
// MFMA 16x16x32 C/D: col(h)=lane&15, row(key)=(lane>>4)*4+reg   [m89].
// ---------------------------------------------------------------------------
__global__ __launch_bounds__(256, 2) void k_fused(
    const float* __restrict__ keys,
    const unsigned short* __restrict__ wk_fr,
    const float* __restrict__ wv_w,
    const float* __restrict__ qp,
    const int* __restrict__ masks,
    float* __restrict__ out) {
  const int t  = threadIdx.x;
  const int w  = t >> 6;      // wave 0..3
  const int l  = t & 63;
  const int lg = l >> 4;      // lane group 0..3
  const int ll = l & 15;
  const int bn = blockIdx.x;

  __shared__ float2 qw_s[HH];     // {qb, wv} per h
  __shared__ float sc[KK];
  __shared__ float red[2];
  __shared__ float po[4][256];

  {
    float2 v0; v0.x = qp[(size_t)bn * HH + t];       v0.y = wv_w[t];
    float2 v1; v1.x = qp[(size_t)bn * HH + t + 256]; v1.y = wv_w[t + 256];
    qw_s[t] = v0;
    qw_s[t + 256] = v1;
  }

  // this wave's 32 rows -> bf16 A-frags (2 chains x 8 slots), kept for PV
  short8 af0[8], af1[8];
  {
    const float* kp0 = keys + (size_t)(bn * KK + w * 32 + ll) * EE + lg * 8;
    const float* kp1 = kp0 + 16 * EE;
    #pragma unroll
    for (int s = 0; s < 8; ++s) {
      float4 x = *(const float4*)(kp0 + s * 32);
      float4 y = *(const float4*)(kp0 + s * 32 + 4);
      short8 f;
      f[0] = bfs(x.x); f[1] = bfs(x.y); f[2] = bfs(x.z); f[3] = bfs(x.w);
      f[4] = bfs(y.x); f[5] = bfs(y.y); f[6] = bfs(y.z); f[7] = bfs(y.w);
      af0[s] = f;
      x = *(const float4*)(kp1 + s * 32);
      y = *(const float4*)(kp1 + s * 32 + 4);
      f[0] = bfs(x.x); f[1] = bfs(x.y); f[2] = bfs(x.z); f[3] = bfs(x.w);
      f[4] = bfs(y.x); f[5] = bfs(y.y); f[6] = bfs(y.z); f[7] = bfs(y.w);
      af1[s] = f;
    }
  }
  __syncthreads();   // qw_s visible; drains all counters -> clean vmcnt slate

  const char* wkb = (const char*)wk_fr;   // 32 tiles x 8192 B, fragment-major
  const int lofs = l * 16;

  float p0[4] = {0.f, 0.f, 0.f, 0.f};
  float p1[4] = {0.f, 0.f, 0.f, 0.f};
  float4 A0, A1, A2, A3, A4, A5, A6, A7;
  float4 B0, B1, B2, B3, B4, B5, B6, B7;

#define ISSUE(b0,b1,b2,b3,b4,b5,b6,b7, ti) {                               \
    const char* p_ = wkb + (size_t)(ti) * 8192 + lofs;                     \
    const char* q_ = p_ + 4096;                                            \
    asm volatile(                                                          \
      "global_load_dwordx4 %0, %8, off\n\t"                                \
      "global_load_dwordx4 %1, %8, off offset:1024\n\t"                    \
      "global_load_dwordx4 %2, %8, off offset:2048\n\t"                    \
      "global_load_dwordx4 %3, %8, off offset:3072\n\t"                    \
      "global_load_dwordx4 %4, %9, off\n\t"                                \
      "global_load_dwordx4 %5, %9, off offset:1024\n\t"                    \
      "global_load_dwordx4 %6, %9, off offset:2048\n\t"                    \
      "global_load_dwordx4 %7, %9, off offset:3072"                        \
      : "=&v"(b0), "=&v"(b1), "=&v"(b2), "=&v"(b3),                        \
        "=&v"(b4), "=&v"(b5), "=&v"(b6), "=&v"(b7)                        \
      : "v"(p_), "v"(q_)); }

#define WAITV(n)  {                                                        \
    asm volatile("s_waitcnt vmcnt(" #n ")" ::: "memory");                  \
    __builtin_amdgcn_sched_barrier(0); }

#define COMPUTE(b0,b1,b2,b3,b4,b5,b6,b7, ii) {                             \
    f32x4 a0 = {0.f, 0.f, 0.f, 0.f};                                       \
    f32x4 a1 = {0.f, 0.f, 0.f, 0.f};                                       \
    short8 f_;                                                             \
    __builtin_amdgcn_s_setprio(1);                                         \
    f_ = __builtin_bit_cast(short8, b0);                                   \
    a0 = __builtin_amdgcn_mfma_f32_16x16x32_bf16(af0[0], f_, a0, 0, 0, 0); \
    a1 = __builtin_amdgcn_mfma_f32_16x16x32_bf16(af1[0], f_, a1, 0, 0, 0); \
    f_ = __builtin_bit_cast(short8, b1);                                   \
    a0 = __builtin_amdgcn_mfma_f32_16x16x32_bf16(af0[1], f_, a0, 0, 0, 0); \
    a1 = __builtin_amdgcn_mfma_f32_16x16x32_bf16(af1[1], f_, a1, 0, 0, 0); \
    f_ = __builtin_bit_cast(short8, b2);                                   \
    a0 = __builtin_amdgcn_mfma_f32_16x16x32_bf16(af0[2], f_, a0, 0, 0, 0); \
    a1 = __builtin_amdgcn_mfma_f32_16x16x32_bf16(af1[2], f_, a1, 0, 0, 0); \
    f_ = __builtin_bit_cast(short8, b3);                                   \
    a0 = __builtin_amdgcn_mfma_f32_16x16x32_bf16(af0[3], f_, a0, 0, 0, 0); \
    a1 = __builtin_amdgcn_mfma_f32_16x16x32_bf16(af1[3], f_, a1, 0, 0, 0); \
    f_ = __builtin_bit_cast(short8, b4);                                   \
    a0 = __builtin_amdgcn_mfma_f32_16x16x32_bf16(af0[4], f_, a0, 0, 0, 0); \
    a1 = __builtin_amdgcn_mfma_f32_16x16x32_bf16(af1[4], f_, a1, 0, 0, 0); \
    f_ = __builtin_bit_cast(short8, b5);                                   \
    a0 = __builtin_amdgcn_mfma_f32_16x16x32_bf16(af0[5], f_, a0, 0, 0, 0); \
    a1 = __builtin_amdgcn_mfma_f32_16x16x32_bf16(af1[5], f_, a1, 0, 0, 0); \
    f_ = __builtin_bit_cast(short8, b6);                                   \
    a0 = __builtin_amdgcn_mfma_f32_16x16x32_bf16(af0[6], f_, a0, 0, 0, 0); \
    a1 = __builtin_amdgcn_mfma_f32_16x16x32_bf16(af1[6], f_, a1, 0, 0, 0); \
    f_ = __builtin_bit_cast(short8, b7);                                   \
    a0 = __builtin_amdgcn_mfma_f32_16x16x32_bf16(af0[7], f_, a0, 0, 0, 0); \
    a1 = __builtin_amdgcn_mfma_f32_16x16x32_bf16(af1[7], f_, a1, 0, 0, 0); \
    __builtin_amdgcn_s_setprio(0);                                         \
    const float2 qw = qw_s[(ii) * 16 + ll];                                \
    _Pragma("unroll") for (int r = 0; r < 4; ++r) {                        \
      p0[r] += qw.y * tanhf_fast(a0[r] + qw.x);                            \
      p1[r] += qw.y * tanhf_fast(a1[r] + qw.x); } }

  ISSUE(A0,A1,A2,A3,A4,A5,A6,A7, 0);
  ISSUE(B0,B1,B2,B3,B4,B5,B6,B7, 1);
  #pragma unroll 1
  for (int i = 0; i < 30; i += 2) {
    WAITV(8);                                 // tile i landed
    COMPUTE(A0,A1,A2,A3,A4,A5,A6,A7, i);
    ISSUE(A0,A1,A2,A3,A4,A5,A6,A7, i + 2);
    WAITV(8);                                 // tile i+1 landed
    COMPUTE(B0,B1,B2,B3,B4,B5,B6,B7, i + 1);
    ISSUE(B0,B1,B2,B3,B4,B5,B6,B7, i + 3);
  }
  WAITV(8);                                   // tile 30
  COMPUTE(A0,A1,A2,A3,A4,A5,A6,A7, 30);
  WAITV(0);                                   // tile 31 (drain)
  COMPUTE(B0,B1,B2,B3,B4,B5,B6,B7, 31);
#undef COMPUTE
#undef WAITV
#undef ISSUE

  // reduce scores over h (16 ll lanes per group)
  #pragma unroll
  for (int r = 0; r < 4; ++r) {
    #pragma unroll
    for (int off = 1; off <= 8; off <<= 1) {
      p0[r] += __shfl_xor(p0[r], off, 64);
      p1[r] += __shfl_xor(p1[r], off, 64);
    }
  }
  if (ll == 0) {
    #pragma unroll
    for (int r = 0; r < 4; ++r) {
      sc[w * 32 + lg * 4 + r]      = p0[r];
      sc[w * 32 + 16 + lg * 4 + r] = p1[r];
    }
  }
  __syncthreads();

  // masked softmax over K=128 (wv_b omitted: softmax shift-invariant)
  if (t < KK) sc[t] += (float)masks[bn * KK + t] * (-1e9f);
  __syncthreads();
  if (t < 64) {
    float a = fmaxf(sc[t], sc[t + 64]);
    #pragma unroll
    for (int off = 32; off >= 1; off >>= 1) a = fmaxf(a, __shfl_xor(a, off, 64));
    if (t == 0) red[0] = a;
  }
  __syncthreads();
  const float m = red[0];
  if (t < KK) sc[t] = expf(sc[t] - m);
  __syncthreads();
  if (t < 64) {
    float a = sc[t] + sc[t + 64];
    #pragma unroll
    for (int off = 32; off >= 1; off >>= 1) a += __shfl_xor(a, off, 64);
    if (t == 0) red[1] = a;
  }
  __syncthreads();
  const float inv = 1.f / red[1];
  if (t < KK) {
    float wgt = sc[t] * inv;
    sc[t] = wgt;
    out[BN * EE + (size_t)bn * KK + t] = wgt;   // attn_weight
  }
  __syncthreads();

  // PV in-register from A-frags: lane (lg,ll) holds rows w*32+ll, w*32+16+ll
  // at e = lg*8 + s*32 + j. Reduce over ll -> po[w][e]; then sum waves.
  {
    const float wgt0 = sc[w * 32 + ll];
    const float wgt1 = sc[w * 32 + 16 + ll];
    #pragma unroll
    for (int s = 0; s < 8; ++s) {
      float pv[8];
      #pragma unroll
      for (int j = 0; j < 8; ++j)
        pv[j] = wgt0 * bf2f(af0[s][j]) + wgt1 * bf2f(af1[s][j]);
      #pragma unroll
      for (int j = 0; j < 8; ++j) {
        #pragma unroll
        for (int off = 1; off <= 8; off <<= 1)
          pv[j] += __shfl_xor(pv[j], off, 64);
      }
      if (ll == 0) {
        float4 v0 = {pv[0], pv[1], pv[2], pv[3]};
        float4 v1 = {pv[4], pv[5], pv[6], pv[7]};
        *(float4*)(&po[w][lg * 8 + s * 32])     = v0;
        *(float4*)(&po[w][lg * 8 + s * 32 + 4]) = v1;
      }
    }
  }
  __syncthreads();
  out[(size_t)bn * EE + t] = po[0][t] + po[1][t] + po[2][t] + po[3][t];
}

// ---------------------------------------------------------------------------
extern "C" void kernel_launch(void* const* d_in, const int* in_sizes, int n_in,
                              void* d_out, int out_size, void* d_ws, size_t ws_size,
                              hipStream_t stream) {
  const float* queries = (const float*)d_in[0];
  const float* keys    = (const float*)d_in[1];
  const int*   masks   = (const int*)d_in[2];
  // d_in[3] = num_neg (unused)
  const float* wk_w = (const float*)d_in[4];
  const float* wk_b = (const float*)d_in[5];
  const float* wq_w = (const float*)d_in[6];
  const float* wq_b = (const float*)d_in[7];
  const float* wv_w = (const float*)d_in[8];
  // d_in[9] = wv_b (softmax shift-invariant -> unused)

  float* out = (float*)d_out;
  float* qp  = (float*)d_ws;                                 // 1 MB
  unsigned short* wk_fr = (unsigned short*)(qp + BN * HH);   // 256 KB

  k_prep<<<128, 256, 0, stream>>>(wk_w, queries, wq_w, wq_b, wk_b, wk_fr, qp);
  k_fused<<<BN, 256, 0, stream>>>(keys, wk_fr, wv_w, qp, masks, out);
}